// Round 13
// baseline (327.720 us; speedup 1.0000x reference)
//
#include <hip/hip_runtime.h>
#include <math.h>

#define NEL 10
#define FD 64
#define NBES 8
#define GG 20
#define HML 16
#define EGB 1280  // geom blocks (polpart rows): 1 edge/thread
#define NUB 5000  // nEpart entries per layer = N/4 (one per EN wave)
#define TKNOT 2048         // table knots (len = k * 5/2048); paired float2 rows
#define TROWS 2049         // builder computes knots 0..2048
#define TBBLK 1025         // ceil(2*2049/4) table-builder blocks (4 waves each)

typedef __attribute__((ext_vector_type(8))) short short8;

__device__ __forceinline__ float wred(float v) {
    #pragma unroll
    for (int off = 32; off > 0; off >>= 1) v += __shfl_down(v, off, 64);
    return v;
}

__device__ __forceinline__ float silu(float h) {
    return h / (1.f + __expf(-h));
}

// bijective XCD-aware block swizzle (m204 form); contiguous chunk per XCD
__device__ __forceinline__ int xcd_swizzle(int bid, int nb) {
    int q = nb >> 3, r = nb & 7;
    int x = bid & 7, i = bid >> 3;
    return (x < r ? x * (q + 1) : r * (q + 1) + (x - r) * q) + i;
}

// Receiver histogram only (tiny; runs before scan).
__global__ __launch_bounds__(256) void hist_k(
    const int* __restrict__ eidx, int* __restrict__ cnt, int E_)
{
    int e = blockIdx.x * 256 + threadIdx.x;
    atomicAdd(&cnt[eidx[E_ + e]], 1);
}

// Single-block shuffle scan (pure prefix-sum of receiver counts).
__global__ __launch_bounds__(1024) void scan_k(
    const int* __restrict__ cnt, int* __restrict__ cur, int N_)
{
    int t = threadIdx.x;
    __shared__ int wtot[16];
    int lane = t & 63, wid = t >> 6;
    int base = t * 20;
    int c[20]; int s = 0;
    bool full = (base + 20 <= N_);
    if (full) {
        #pragma unroll
        for (int i = 0; i < 5; ++i) {
            int4 v4 = *(const int4*)&cnt[base + i * 4];
            c[i*4+0] = v4.x; c[i*4+1] = v4.y; c[i*4+2] = v4.z; c[i*4+3] = v4.w;
        }
        #pragma unroll
        for (int i = 0; i < 20; ++i) s += c[i];
    } else {
        #pragma unroll
        for (int i = 0; i < 20; ++i) { int idx = base + i; c[i] = (idx < N_) ? cnt[idx] : 0; s += c[i]; }
    }
    int v = s;
    #pragma unroll
    for (int off = 1; off < 64; off <<= 1) {
        int u = __shfl_up(v, off, 64);
        if (lane >= off) v += u;
    }
    if (lane == 63) wtot[wid] = v;
    __syncthreads();
    if (wid == 0 && lane < 16) {
        int wv = wtot[lane];
        #pragma unroll
        for (int off = 1; off < 16; off <<= 1) {
            int u = __shfl_up(wv, off, 64);
            if (lane >= off) wv += u;
        }
        wtot[lane] = wv;
    }
    __syncthreads();
    int ex = (wid > 0 ? wtot[wid - 1] : 0) + (v - s);
    if (full) {
        int o[20];
        #pragma unroll
        for (int i = 0; i < 20; ++i) { o[i] = ex; ex += c[i]; }
        #pragma unroll
        for (int i = 0; i < 5; ++i)
            *(int4*)&cur[base + i * 4] = make_int4(o[i*4+0], o[i*4+1], o[i*4+2], o[i*4+3]);
    } else {
        #pragma unroll
        for (int i = 0; i < 20; ++i) {
            int idx = base + i;
            if (idx < N_) { cur[idx] = ex; ex += c[i]; }
        }
    }
}

// Fused: blocks [0,EGB) = geom scatter ({snd|rcv, len} 8B record at sorted slot);
// [EGB, EGB+TBBLK) = paired radial table build (wave per (layer,knot));
// [EGB+TBBLK, ...) = node init (scal/spec/q/E0). Setup hides under the scatter.
__global__ __launch_bounds__(256) void setup_geom_k(
    const float* __restrict__ pos, const int* __restrict__ eidx,
    const float* __restrict__ flux_w, int* __restrict__ cur,
    uint2* __restrict__ recs, float* __restrict__ polpart,
    const float* __restrict__ attrs, const float* __restrict__ ae,
    const float* __restrict__ fc, const float* __restrict__ embed_w,
    int* __restrict__ spec, float* __restrict__ q, float* __restrict__ out,
    float* __restrict__ scal,
    const float* __restrict__ w1, const float* __restrict__ b1,
    const float* __restrict__ w2, float* __restrict__ tab,
    int N_, int E_, int ng)
{
    int bid = blockIdx.x, t = threadIdx.x;
    const float PI = 3.14159265358979323846f;
    if (bid < EGB) {
        // ---- geom scatter path (1 edge/thread) ----
        __shared__ float lpol[GG * 3];
        for (int i = t; i < GG * 3; i += 256) lpol[i] = 0.f;
        __syncthreads();
        int e = bid * 256 + t;
        if (e < E_) {
            float fw[NBES];
            #pragma unroll
            for (int i = 0; i < NBES; ++i) fw[i] = flux_w[i] + flux_w[NBES + i];
            unsigned int magic = (unsigned int)(0xFFFFFFFFull / (unsigned int)ng) + 1u;
            int s = eidx[e], r = eidx[E_ + e];
            float dx = pos[(size_t)r*3+0] - pos[(size_t)s*3+0];
            float dy = pos[(size_t)r*3+1] - pos[(size_t)s*3+1];
            float dz = pos[(size_t)r*3+2] - pos[(size_t)s*3+2];
            float len = sqrtf(dx*dx + dy*dy + dz*dz + 1e-12f);
            float x = len * 0.2f;
            float u = 0.f;
            if (x < 1.f) {
                float x2 = x * x;
                float x5 = x2 * x2 * x;
                u = 1.f - 21.f * x5 + 35.f * x5 * x - 15.f * x5 * x2;
            }
            float pref = 0.6324555320336759f / len * u;
            float theta = PI * x;
            float s1, c1;
            __sincosf(theta, &s1, &c1);
            float c2 = 2.f * c1;
            float sp_ = 0.f, sn = s1;
            float flux = 0.f;
            #pragma unroll
            for (int i = 0; i < NBES; ++i) {
                flux += pref * sn * fw[i];
                float n1 = c2 * sn - sp_; sp_ = sn; sn = n1;
            }
            int p = atomicAdd(&cur[r], 1);
            recs[p] = make_uint2((unsigned int)s | ((unsigned int)r << 16),
                                 __float_as_uint(len));
            int g = (int)__umulhi((unsigned int)r, magic);
            atomicAdd(&lpol[g*3+0], flux * dx);
            atomicAdd(&lpol[g*3+1], flux * dy);
            atomicAdd(&lpol[g*3+2], flux * dz);
        }
        __syncthreads();
        for (int i = t; i < GG * 3; i += 256) polpart[bid * (GG * 3) + i] = lpol[i];
    } else if (bid < EGB + TBBLK) {
        // ---- paired radial table build: wave (l,kk) -> R_kk; writes
        //      tab entry kk (.x) and entry kk-1 (.y) ----
        if (bid == EGB && t < GG) out[t] = 0.f;   // total-energy accumulators
        int widg = (bid - EGB) * 4 + (t >> 6);
        if (widg < 2 * TROWS) {
            int l = widg / TROWS;
            int kk = widg - l * TROWS;
            int f = t & 63;
            float len = fmaxf((float)kk * (5.f / (float)TKNOT), 1e-6f);
            float x = len * 0.2f;
            float u = 0.f;
            if (x < 1.f) {
                float x2 = x * x;
                float x5 = x2 * x2 * x;
                u = 1.f - 21.f * x5 + 35.f * x5 * x - 15.f * x5 * x2;
            }
            float pref = 0.6324555320336759f / len * u;
            float theta = PI * x;
            float s1, c1;
            __sincosf(theta, &s1, &c1);
            float c2 = 2.f * c1;
            float sp_ = 0.f, sn = s1;
            float ef[NBES];
            #pragma unroll
            for (int i = 0; i < NBES; ++i) {
                ef[i] = pref * sn;
                float n1 = c2 * sn - sp_; sp_ = sn; sn = n1;
            }
            float h = b1[l * FD + f];
            #pragma unroll
            for (int j = 0; j < NBES; ++j)
                h = fmaf(ef[j], w1[l * 512 + j * 64 + f], h);
            h = silu(h);
            float o = 0.f;
            #pragma unroll
            for (int m = 0; m < 64; ++m)
                o = fmaf(__shfl(h, m, 64), w2[(size_t)l * 4096 + m * 64 + f], o);
            float* tbase = tab + (size_t)l * TKNOT * 64 * 2;
            if (kk < TKNOT) tbase[((size_t)kk * 64 + f) * 2 + 0] = o;        // .x
            if (kk > 0)     tbase[((size_t)(kk - 1) * 64 + f) * 2 + 1] = o;  // .y
        }
    } else {
        // ---- node init: scal embed, spec, q=fc, E0 ----
        int idx = (bid - (EGB + TBBLK)) * 256 + t;
        int lane = t & 63;
        int n = idx >> 6;
        bool pred = (lane < NEL) && (attrs[(size_t)n * NEL + lane] > 0.5f);
        unsigned long long m = __ballot(pred);
        int sp = (int)__builtin_ctzll(m);
        scal[idx] = embed_w[sp * FD + lane];
        if (lane == 0) { spec[n] = sp; q[n] = fc[sp]; out[GG + n] = ae[sp]; }
    }
}

// Fused edge+node pass: wave owns 4 consecutive receivers (edge range from
// cur end-offsets; ranges contiguous in sorted order). Radial MLP via paired
// float2 table lerp. Segmented reduce deposits into 4 named registers — NO
// agg0 memory, NO atomics. Each receiver's node update (prod/readout/q/ro2)
// finishes in-register (R11 wave-parallel ro2 form). nEpart per wave.
__global__ __launch_bounds__(256, 4) void edge_node_k(
    const uint2* __restrict__ recs, const float* __restrict__ tab,
    const int* __restrict__ cur, float* __restrict__ scal,
    const int* __restrict__ spec, const float* __restrict__ prod_w,
    const float* __restrict__ readout_w, const float* __restrict__ ro2_w1,
    const float* __restrict__ ro2_b1, const float* __restrict__ ro2_w2,
    const float* __restrict__ charge_w, float* __restrict__ q,
    float* __restrict__ out_nodeE, float* __restrict__ nEpart,
    int layer, int last, int N_)
{
    __shared__ float vsh[4][FD];
    int t = threadIdx.x, w = t >> 6, lane = t & 63;
    int xb = xcd_swizzle(blockIdx.x, gridDim.x);
    int W = xb * 4 + w;                 // wave id = group of 4 receivers
    int r0 = W * 4;
    int e0 = (r0 == 0) ? 0 : cur[r0 - 1];
    int e1 = cur[r0 + 3];
    const float* tb = tab + (size_t)layer * TKNOT * 64 * 2;

    float a0 = 0.f, a1 = 0.f, a2 = 0.f, a3 = 0.f;
    int curR = r0; float run = 0.f;

    for (int base = e0; base < e1; base += 64) {
        int nn = e1 - base; if (nn > 64) nn = 64;
        uint2 rec = (base + lane < e1) ? recs[base + lane] : make_uint2(0u, 0u);
        float ln = __uint_as_float(rec.y);
        float ttf = ln * ((float)TKNOT / 5.f);
        int k0 = (int)ttf; k0 = max(0, min(k0, TKNOT - 1));
        float fr = fminf(fmaxf(ttf - (float)k0, 0.f), 1.f);
        unsigned int pk = ((unsigned int)k0 << 16) |
                          (unsigned int)fminf(fr * 65536.f, 65535.f);
        #pragma unroll 1
        for (int sub = 0; sub < 4; ++sub) {
            int sb = sub * 16;
            if (sb >= nn) break;
            int cnt16 = nn - sb; if (cnt16 > 16) cnt16 = 16;
            unsigned int idv[16], pkk[16];
            #pragma unroll
            for (int k = 0; k < 16; ++k) {
                idv[k] = __builtin_amdgcn_readlane(rec.x, sb + k);
                pkk[k] = __builtin_amdgcn_readlane(pk, sb + k);
            }
            float2 rab[16]; float sw[16];
            #pragma unroll
            for (int k = 0; k < 16; ++k) {
                rab[k] = *(const float2*)&tb[((size_t)(pkk[k] >> 16) * 64 + lane) * 2];
                sw[k]  = scal[(size_t)(idv[k] & 0xffffu) * FD + lane];
            }
            #pragma unroll
            for (int k = 0; k < 16; ++k) {
                if (k >= cnt16) break;
                int r = (int)(idv[k] >> 16);
                float fk = (float)(pkk[k] & 0xffffu) * (1.f / 65536.f);
                float R = fmaf(fk, rab[k].y - rab[k].x, rab[k].x);
                float v = R * sw[k];
                if (r != curR) {
                    int ri = curR - r0;
                    if (ri == 0) a0 = run; else if (ri == 1) a1 = run;
                    else if (ri == 2) a2 = run; else a3 = run;
                    curR = r; run = v;
                } else {
                    run += v;
                }
            }
        }
    }
    {
        int ri = curR - r0;
        if (ri == 0) a0 = run; else if (ri == 1) a1 = run;
        else if (ri == 2) a2 = run; else a3 = run;
    }

    float neAcc = 0.f;
    #pragma unroll
    for (int i = 0; i < 4; ++i) {
        float acc = (i == 0) ? a0 : (i == 1) ? a1 : (i == 2) ? a2 : a3;
        int rr = r0 + i;
        float a = acc * 0.0625f;
        int sp = spec[rr];
        size_t idx = (size_t)rr * FD + lane;
        float v = a + a * a + scal[idx] * prod_w[(layer * NEL + sp) * FD + lane];
        if (!last) scal[idx] = v;          // next layer's input (final layer: dead)
        float ne;
        if (!last) {
            ne = wred(v * readout_w[layer * FD + lane]);
        } else {
            vsh[w][lane] = v;              // wave-private, in-order DS
            int l16 = lane & 15, qq = lane >> 4;
            float hp = 0.f;
            #pragma unroll
            for (int ff = 0; ff < 16; ++ff) {
                int fidx = qq * 16 + ff;
                hp += vsh[w][fidx] * ro2_w1[fidx * HML + l16];
            }
            hp += __shfl_down(hp, 32, 64);
            hp += __shfl_down(hp, 16, 64);   // lanes 0..15 hold full sum
            float h = 0.f;
            if (lane < HML) h = silu(ro2_b1[lane] + hp) * ro2_w2[lane];
            ne = wred(h);
        }
        float qs = wred(v * charge_w[layer * FD + lane]);
        if (lane == 0) {
            out_nodeE[rr] += ne;           // exclusive owner — no atomics
            q[rr] += qs;
            neAcc += ne;
        }
    }
    if (lane == 0) nEpart[layer * NUB + W] = neAcc;
}

// Coulomb via triangular 64x64 chunk pairs (136/graph) + 1 reduce block/graph.
__global__ __launch_bounds__(256) void coulomb_final_k(
    const float* __restrict__ q, const float* __restrict__ pos,
    const int* __restrict__ spec, const float* __restrict__ ae,
    const float* __restrict__ fc, const float* __restrict__ nEpart,
    const float* __restrict__ polpart, float* __restrict__ out,
    int N_, int ng)
{
    __shared__ float sh[260];
    int vb = blockIdx.x;
    int g = vb / 137, rem = vb % 137;
    int t = threadIdx.x, lane = t & 63, w = t >> 6;

    if (rem < 136) {
        int a = 0, r2 = rem;
        while (r2 >= 16 - a) { r2 -= 16 - a; ++a; }
        int b = a + r2;
        const float* qg = q + (size_t)g * ng;
        const float* pg = pos + (size_t)g * ng * 3;
        float* qs_ = sh; float* jx = sh + 64; float* jy = sh + 128; float* jz = sh + 192;
        if (t < 64) {
            int j = b * 64 + t;
            bool ok = j < ng;
            qs_[t] = ok ? qg[j] : 0.f;
            jx[t] = ok ? pg[(size_t)j*3+0] : 0.f;
            jy[t] = ok ? pg[(size_t)j*3+1] : 0.f;
            jz[t] = ok ? pg[(size_t)j*3+2] : 0.f;
        }
        __syncthreads();
        int i = a * 64 + lane;
        float accu = 0.f;
        if (i < ng) {
            float qi = qg[i];
            float xi = pg[(size_t)i*3+0], yi = pg[(size_t)i*3+1], zi = pg[(size_t)i*3+2];
            #pragma unroll 4
            for (int k = 0; k < 16; ++k) {
                int jj = w * 16 + k;                  // wave-uniform -> LDS broadcast
                int j = b * 64 + jj;
                float dx = xi - jx[jj], dy = yi - jy[jj], dz = zi - jz[jj];
                float d2 = dx*dx + dy*dy + dz*dz + 1e-12f;
                float rinv = __frsqrt_rn(d2);
                float r = d2 * rinv;
                float x = 0.5f * r;
                float tt = __frcp_rn(1.f + 0.3275911f * x);
                float poly = ((((1.061405429f*tt - 1.453152027f)*tt + 1.421413741f)*tt
                               - 0.284496736f)*tt + 0.254829592f)*tt;
                float erfv = 1.f - poly * __expf(-x * x);
                float kern = (j == i) ? 0.f : erfv * rinv;
                accu += qi * qs_[jj] * kern;
            }
        }
        accu = wred(accu);
        if (lane == 0) sh[256 + w] = accu;
        __syncthreads();
        if (t == 0) {
            float s = sh[256] + sh[257] + sh[258] + sh[259];
            atomicAdd(&out[g], (a == b) ? 0.5f * s : s);
        }
    } else {
        float se0 = 0.f, sq = 0.f, p0 = 0.f, p1 = 0.f, p2 = 0.f, s0 = 0.f, s1 = 0.f;
        for (int n = g * ng + t; n < (g + 1) * ng; n += 256) {
            int sp = spec[n];
            float fq = fc[sp];
            se0 += ae[sp];
            sq += q[n];
            p0 += fq * pos[(size_t)n*3+0];
            p1 += fq * pos[(size_t)n*3+1];
            p2 += fq * pos[(size_t)n*3+2];
        }
        if (t < 250) {
            int b = g * 250 + t;
            s0 = nEpart[b];
            s1 = nEpart[NUB + b];
        }
        for (int b = t; b < EGB; b += 256) {
            p0 += polpart[b * (GG * 3) + g * 3 + 0];
            p1 += polpart[b * (GG * 3) + g * 3 + 1];
            p2 += polpart[b * (GG * 3) + g * 3 + 2];
        }
        float vals[7] = {se0, s0, s1, sq, p0, p1, p2};
        float* red = sh;
        #pragma unroll
        for (int k = 0; k < 7; ++k) {
            float r = wred(vals[k]);
            if (lane == 0) red[w * 8 + k] = r;
        }
        __syncthreads();
        if (t < 7) sh[64 + t] = red[t] + red[8 + t] + red[16 + t] + red[24 + t];
        __syncthreads();
        if (t == 0) {
            float a0 = sh[64], a1 = sh[65], a2 = sh[66];
            atomicAdd(&out[g], a0 + a1 + a2);
            float* contrib = out + GG + N_;
            contrib[g*3+0] = a0; contrib[g*3+1] = a1; contrib[g*3+2] = a2;
            float* pol = contrib + GG * 3;
            pol[g*3+0] = sh[68]; pol[g*3+1] = sh[69]; pol[g*3+2] = sh[70];
            float* qt = pol + GG * 3;
            qt[g] = sh[67];
        }
    }
}

extern "C" void kernel_launch(void* const* d_in, const int* in_sizes, int n_in,
                              void* d_out, int out_size, void* d_ws, size_t ws_size,
                              hipStream_t stream)
{
    const float* node_attrs      = (const float*)d_in[0];
    const float* positions       = (const float*)d_in[1];
    const int*   edge_index      = (const int*)d_in[2];
    const float* atomic_energies = (const float*)d_in[5];
    const float* embed_w         = (const float*)d_in[6];
    const float* radial_w1       = (const float*)d_in[7];
    const float* radial_b1       = (const float*)d_in[8];
    const float* radial_w2       = (const float*)d_in[9];
    const float* prod_w          = (const float*)d_in[10];
    const float* readout_w       = (const float*)d_in[11];
    const float* ro2_w1          = (const float*)d_in[12];
    const float* ro2_b1          = (const float*)d_in[13];
    const float* ro2_w2          = (const float*)d_in[14];
    const float* charge_w        = (const float*)d_in[15];
    const float* flux_w          = (const float*)d_in[16];
    const float* formal_charges  = (const float*)d_in[17];

    int N = in_sizes[0] / NEL;     // 20000
    int E = in_sizes[2] / 2;       // 320000
    int ng = N / GG;               // 1000

    float* ws      = (float*)d_ws;
    float* scal    = ws;                                   // [N,64]
    int*   cnt     = (int*)(scal + (size_t)N * FD);        // [N]  (memset)
    int*   cur     = cnt + N;                              // [N]  (scan -> geom-mutated to end offsets)
    uint2* recs    = (uint2*)(cur + N);                    // [E] {snd|rcv<<16, len} sorted
    float* q       = (float*)(recs + E);                   // [N]
    int*   spec    = (int*)(q + N);                        // [N]
    float* nEpart  = (float*)(spec + N);                   // [2*NUB]
    float* polpart = nEpart + 2 * NUB;                     // [EGB*60]
    float* tab     = polpart + EGB * (GG * 3);             // [2][TKNOT][64] float2 paired

    float* out = (float*)d_out;
    float* out_nodeE = out + GG;

    hipMemsetAsync(cnt, 0, (size_t)N * sizeof(int), stream);

    hist_k<<<E / 256, 256, 0, stream>>>(edge_index, cnt, E);
    scan_k<<<1, 1024, 0, stream>>>(cnt, cur, N);
    setup_geom_k<<<EGB + TBBLK + (N * FD) / 256, 256, 0, stream>>>(
        positions, edge_index, flux_w, cur, recs, polpart,
        node_attrs, atomic_energies, formal_charges, embed_w,
        spec, q, out, scal, radial_w1, radial_b1, radial_w2, tab, N, E, ng);

    for (int l = 0; l < 2; ++l) {
        edge_node_k<<<N / 16, 256, 0, stream>>>(
            recs, tab, cur, scal, spec, prod_w, readout_w,
            ro2_w1, ro2_b1, ro2_w2, charge_w, q, out_nodeE, nEpart,
            l, (l == 1) ? 1 : 0, N);
    }

    coulomb_final_k<<<GG * 137, 256, 0, stream>>>(
        q, positions, spec, atomic_energies, formal_charges,
        nEpart, polpart, out, N, ng);
}

// Round 15
// 227.107 us; speedup vs baseline: 1.4430x; 1.4430x over previous
//
#include <hip/hip_runtime.h>
#include <math.h>

#define NEL 10
#define FD 64
#define NBES 8
#define GG 20
#define HML 16
#define EGB 1280  // geom blocks (polpart rows): 1 edge/thread
#define NUB 5000  // nEpart entries per layer = N/4 (one per EN wave)
#define TKNOT 2048         // table knots (len = k * 5/2048); paired float2 rows
#define TROWS 2049         // builder computes knots 0..2048
#define TBBLK 1025         // ceil(2*2049/4) table-builder blocks (4 waves each)

__device__ __forceinline__ float wred(float v) {
    #pragma unroll
    for (int off = 32; off > 0; off >>= 1) v += __shfl_down(v, off, 64);
    return v;
}

__device__ __forceinline__ float silu(float h) {
    return h / (1.f + __expf(-h));
}

// bijective XCD-aware block swizzle (m204 form); contiguous chunk per XCD
__device__ __forceinline__ int xcd_swizzle(int bid, int nb) {
    int q = nb >> 3, r = nb & 7;
    int x = bid & 7, i = bid >> 3;
    return (x < r ? x * (q + 1) : r * (q + 1) + (x - r) * q) + i;
}

// Receiver histogram only (tiny; runs before scan).
__global__ __launch_bounds__(256) void hist_k(
    const int* __restrict__ eidx, int* __restrict__ cnt, int E_)
{
    int e = blockIdx.x * 256 + threadIdx.x;
    atomicAdd(&cnt[eidx[E_ + e]], 1);
}

// Single-block shuffle scan (pure prefix-sum of receiver counts).
__global__ __launch_bounds__(1024) void scan_k(
    const int* __restrict__ cnt, int* __restrict__ cur, int N_)
{
    int t = threadIdx.x;
    __shared__ int wtot[16];
    int lane = t & 63, wid = t >> 6;
    int base = t * 20;
    int c[20]; int s = 0;
    bool full = (base + 20 <= N_);
    if (full) {
        #pragma unroll
        for (int i = 0; i < 5; ++i) {
            int4 v4 = *(const int4*)&cnt[base + i * 4];
            c[i*4+0] = v4.x; c[i*4+1] = v4.y; c[i*4+2] = v4.z; c[i*4+3] = v4.w;
        }
        #pragma unroll
        for (int i = 0; i < 20; ++i) s += c[i];
    } else {
        #pragma unroll
        for (int i = 0; i < 20; ++i) { int idx = base + i; c[i] = (idx < N_) ? cnt[idx] : 0; s += c[i]; }
    }
    int v = s;
    #pragma unroll
    for (int off = 1; off < 64; off <<= 1) {
        int u = __shfl_up(v, off, 64);
        if (lane >= off) v += u;
    }
    if (lane == 63) wtot[wid] = v;
    __syncthreads();
    if (wid == 0 && lane < 16) {
        int wv = wtot[lane];
        #pragma unroll
        for (int off = 1; off < 16; off <<= 1) {
            int u = __shfl_up(wv, off, 64);
            if (lane >= off) wv += u;
        }
        wtot[lane] = wv;
    }
    __syncthreads();
    int ex = (wid > 0 ? wtot[wid - 1] : 0) + (v - s);
    if (full) {
        int o[20];
        #pragma unroll
        for (int i = 0; i < 20; ++i) { o[i] = ex; ex += c[i]; }
        #pragma unroll
        for (int i = 0; i < 5; ++i)
            *(int4*)&cur[base + i * 4] = make_int4(o[i*4+0], o[i*4+1], o[i*4+2], o[i*4+3]);
    } else {
        #pragma unroll
        for (int i = 0; i < 20; ++i) {
            int idx = base + i;
            if (idx < N_) { cur[idx] = ex; ex += c[i]; }
        }
    }
}

// Fused: blocks [0,EGB) = geom scatter ({snd|rcv, len} 8B record at sorted slot);
// [EGB, EGB+TBBLK) = paired radial table build (wave per (layer,knot));
// [EGB+TBBLK, ...) = node init (scal_a/spec/q/E0). Setup hides under the scatter.
__global__ __launch_bounds__(256) void setup_geom_k(
    const float* __restrict__ pos, const int* __restrict__ eidx,
    const float* __restrict__ flux_w, int* __restrict__ cur,
    uint2* __restrict__ recs, float* __restrict__ polpart,
    const float* __restrict__ attrs, const float* __restrict__ ae,
    const float* __restrict__ fc, const float* __restrict__ embed_w,
    int* __restrict__ spec, float* __restrict__ q, float* __restrict__ out,
    float* __restrict__ scal,
    const float* __restrict__ w1, const float* __restrict__ b1,
    const float* __restrict__ w2, float* __restrict__ tab,
    int N_, int E_, int ng)
{
    int bid = blockIdx.x, t = threadIdx.x;
    const float PI = 3.14159265358979323846f;
    if (bid < EGB) {
        // ---- geom scatter path (1 edge/thread) ----
        __shared__ float lpol[GG * 3];
        for (int i = t; i < GG * 3; i += 256) lpol[i] = 0.f;
        __syncthreads();
        int e = bid * 256 + t;
        if (e < E_) {
            float fw[NBES];
            #pragma unroll
            for (int i = 0; i < NBES; ++i) fw[i] = flux_w[i] + flux_w[NBES + i];
            unsigned int magic = (unsigned int)(0xFFFFFFFFull / (unsigned int)ng) + 1u;
            int s = eidx[e], r = eidx[E_ + e];
            float dx = pos[(size_t)r*3+0] - pos[(size_t)s*3+0];
            float dy = pos[(size_t)r*3+1] - pos[(size_t)s*3+1];
            float dz = pos[(size_t)r*3+2] - pos[(size_t)s*3+2];
            float len = sqrtf(dx*dx + dy*dy + dz*dz + 1e-12f);
            float x = len * 0.2f;
            float u = 0.f;
            if (x < 1.f) {
                float x2 = x * x;
                float x5 = x2 * x2 * x;
                u = 1.f - 21.f * x5 + 35.f * x5 * x - 15.f * x5 * x2;
            }
            float pref = 0.6324555320336759f / len * u;
            float theta = PI * x;
            float s1, c1;
            __sincosf(theta, &s1, &c1);
            float c2 = 2.f * c1;
            float sp_ = 0.f, sn = s1;
            float flux = 0.f;
            #pragma unroll
            for (int i = 0; i < NBES; ++i) {
                flux += pref * sn * fw[i];
                float n1 = c2 * sn - sp_; sp_ = sn; sn = n1;
            }
            int p = atomicAdd(&cur[r], 1);
            recs[p] = make_uint2((unsigned int)s | ((unsigned int)r << 16),
                                 __float_as_uint(len));
            int g = (int)__umulhi((unsigned int)r, magic);
            atomicAdd(&lpol[g*3+0], flux * dx);
            atomicAdd(&lpol[g*3+1], flux * dy);
            atomicAdd(&lpol[g*3+2], flux * dz);
        }
        __syncthreads();
        for (int i = t; i < GG * 3; i += 256) polpart[bid * (GG * 3) + i] = lpol[i];
    } else if (bid < EGB + TBBLK) {
        // ---- paired radial table build: wave (l,kk) -> R_kk; writes
        //      tab entry kk (.x) and entry kk-1 (.y) ----
        if (bid == EGB && t < GG) out[t] = 0.f;   // total-energy accumulators
        int widg = (bid - EGB) * 4 + (t >> 6);
        if (widg < 2 * TROWS) {
            int l = widg / TROWS;
            int kk = widg - l * TROWS;
            int f = t & 63;
            float len = fmaxf((float)kk * (5.f / (float)TKNOT), 1e-6f);
            float x = len * 0.2f;
            float u = 0.f;
            if (x < 1.f) {
                float x2 = x * x;
                float x5 = x2 * x2 * x;
                u = 1.f - 21.f * x5 + 35.f * x5 * x - 15.f * x5 * x2;
            }
            float pref = 0.6324555320336759f / len * u;
            float theta = PI * x;
            float s1, c1;
            __sincosf(theta, &s1, &c1);
            float c2 = 2.f * c1;
            float sp_ = 0.f, sn = s1;
            float ef[NBES];
            #pragma unroll
            for (int i = 0; i < NBES; ++i) {
                ef[i] = pref * sn;
                float n1 = c2 * sn - sp_; sp_ = sn; sn = n1;
            }
            float h = b1[l * FD + f];
            #pragma unroll
            for (int j = 0; j < NBES; ++j)
                h = fmaf(ef[j], w1[l * 512 + j * 64 + f], h);
            h = silu(h);
            float o = 0.f;
            #pragma unroll
            for (int m = 0; m < 64; ++m)
                o = fmaf(__shfl(h, m, 64), w2[(size_t)l * 4096 + m * 64 + f], o);
            float* tbase = tab + (size_t)l * TKNOT * 64 * 2;
            if (kk < TKNOT) tbase[((size_t)kk * 64 + f) * 2 + 0] = o;        // .x
            if (kk > 0)     tbase[((size_t)(kk - 1) * 64 + f) * 2 + 1] = o;  // .y
        }
    } else {
        // ---- node init: scal_a embed, spec, q=fc, E0 ----
        int idx = (bid - (EGB + TBBLK)) * 256 + t;
        int lane = t & 63;
        int n = idx >> 6;
        bool pred = (lane < NEL) && (attrs[(size_t)n * NEL + lane] > 0.5f);
        unsigned long long m = __ballot(pred);
        int sp = (int)__builtin_ctzll(m);
        scal[idx] = embed_w[sp * FD + lane];
        if (lane == 0) { spec[n] = sp; q[n] = fc[sp]; out[GG + n] = ae[sp]; }
    }
}

// Fused edge+node pass, ping-pong scal (race-free): reads scal_in (written
// by the previous dispatch), writes scal_out for its 4 exclusively-owned
// receivers. Radial MLP via paired float2 table lerp. Segmented reduce into
// 4 named registers — no agg0 memory, no atomics. Tail handled by sentinel
// receiver + wave-uniform mask (NO break inside unrolled loops — keeps all
// arrays statically indexed; R13's break caused scratch spills).
__global__ __launch_bounds__(256, 4) void edge_node_k(
    const uint2* __restrict__ recs, const float* __restrict__ tab,
    const int* __restrict__ cur,
    const float* __restrict__ scal_in, float* __restrict__ scal_out,
    const int* __restrict__ spec, const float* __restrict__ prod_w,
    const float* __restrict__ readout_w, const float* __restrict__ ro2_w1,
    const float* __restrict__ ro2_b1, const float* __restrict__ ro2_w2,
    const float* __restrict__ charge_w, float* __restrict__ q,
    float* __restrict__ out_nodeE, float* __restrict__ nEpart,
    int layer, int last, int N_)
{
    __shared__ float vsh[4][FD];
    int t = threadIdx.x, w = t >> 6, lane = t & 63;
    int xb = xcd_swizzle(blockIdx.x, gridDim.x);
    int W = xb * 4 + w;                 // wave id = group of 4 receivers
    int r0 = W * 4;
    int e0 = (r0 == 0) ? 0 : cur[r0 - 1];
    int e1 = cur[r0 + 3];
    const float* tb = tab + (size_t)layer * TKNOT * 64 * 2;

    float a0 = 0.f, a1 = 0.f, a2 = 0.f, a3 = 0.f;
    int curR = r0; float run = 0.f;

    for (int base = e0; base < e1; base += 64) {
        int nn = e1 - base; if (nn > 64) nn = 64;
        uint2 rec;
        if (base + lane < e1) rec = recs[base + lane];
        else rec = make_uint2((unsigned int)(r0 + 3) << 16, 0u);  // sentinel rcv
        float ln = __uint_as_float(rec.y);
        float ttf = ln * ((float)TKNOT / 5.f);
        int k0 = (int)ttf; k0 = max(0, min(k0, TKNOT - 1));
        float frl = fminf(fmaxf(ttf - (float)k0, 0.f), 1.f);
        int offl = k0 * 128;               // float index of paired row base

        #pragma unroll 1
        for (int sub = 0; sub < 4; ++sub) {
            int sb = sub * 16;
            if (sb >= nn) break;           // runtime loop level only
            unsigned int idv[16]; int offk[16]; float frk[16];
            #pragma unroll
            for (int k = 0; k < 16; ++k) {
                int pp = sb + k;
                idv[k] = __builtin_amdgcn_readlane(rec.x, pp);
                offk[k] = __builtin_amdgcn_readlane(offl, pp);
                frk[k] = __uint_as_float((unsigned int)__builtin_amdgcn_readlane(
                             __float_as_uint(frl), pp));
            }
            float2 rab[16]; float sw[16];
            #pragma unroll
            for (int k = 0; k < 16; ++k) {
                rab[k] = *(const float2*)&tb[(size_t)offk[k] + lane * 2];
                sw[k]  = scal_in[(size_t)(idv[k] & 0xffffu) * FD + lane];
            }
            #pragma unroll
            for (int k = 0; k < 16; ++k) {
                int r = (int)(idv[k] >> 16);
                float R = fmaf(frk[k], rab[k].y - rab[k].x, rab[k].x);
                float v = ((sb + k) < nn) ? R * sw[k] : 0.f;  // wave-uniform mask
                if (r != curR) {                               // wave-uniform branch
                    int ri = curR - r0;
                    if (ri == 0) a0 = run; else if (ri == 1) a1 = run;
                    else if (ri == 2) a2 = run; else a3 = run;
                    curR = r; run = v;
                } else {
                    run += v;
                }
            }
        }
    }
    {
        int ri = curR - r0;
        if (ri == 0) a0 = run; else if (ri == 1) a1 = run;
        else if (ri == 2) a2 = run; else a3 = run;
    }

    float neAcc = 0.f;
    #pragma unroll
    for (int i = 0; i < 4; ++i) {
        float acc = (i == 0) ? a0 : (i == 1) ? a1 : (i == 2) ? a2 : a3;
        int rr = r0 + i;
        float a = acc * 0.0625f;
        int sp = spec[rr];
        size_t idx = (size_t)rr * FD + lane;
        float v = a + a * a + scal_in[idx] * prod_w[(layer * NEL + sp) * FD + lane];
        if (!last) scal_out[idx] = v;      // next layer's input (final layer: dead)
        float ne;
        if (!last) {
            ne = wred(v * readout_w[layer * FD + lane]);
        } else {
            vsh[w][lane] = v;              // wave-private, in-order DS
            int l16 = lane & 15, qq = lane >> 4;
            float hp = 0.f;
            #pragma unroll
            for (int ff = 0; ff < 16; ++ff) {
                int fidx = qq * 16 + ff;
                hp += vsh[w][fidx] * ro2_w1[fidx * HML + l16];
            }
            hp += __shfl_down(hp, 32, 64);
            hp += __shfl_down(hp, 16, 64);   // lanes 0..15 hold full sum
            float h = 0.f;
            if (lane < HML) h = silu(ro2_b1[lane] + hp) * ro2_w2[lane];
            ne = wred(h);
        }
        float qs = wred(v * charge_w[layer * FD + lane]);
        if (lane == 0) {
            out_nodeE[rr] += ne;           // exclusive owner — no atomics
            q[rr] += qs;
            neAcc += ne;
        }
    }
    if (lane == 0) nEpart[layer * NUB + W] = neAcc;
}

// Coulomb via triangular 64x64 chunk pairs (136/graph) + 1 reduce block/graph.
__global__ __launch_bounds__(256) void coulomb_final_k(
    const float* __restrict__ q, const float* __restrict__ pos,
    const int* __restrict__ spec, const float* __restrict__ ae,
    const float* __restrict__ fc, const float* __restrict__ nEpart,
    const float* __restrict__ polpart, float* __restrict__ out,
    int N_, int ng)
{
    __shared__ float sh[260];
    int vb = blockIdx.x;
    int g = vb / 137, rem = vb % 137;
    int t = threadIdx.x, lane = t & 63, w = t >> 6;

    if (rem < 136) {
        int a = 0, r2 = rem;
        while (r2 >= 16 - a) { r2 -= 16 - a; ++a; }
        int b = a + r2;
        const float* qg = q + (size_t)g * ng;
        const float* pg = pos + (size_t)g * ng * 3;
        float* qs_ = sh; float* jx = sh + 64; float* jy = sh + 128; float* jz = sh + 192;
        if (t < 64) {
            int j = b * 64 + t;
            bool ok = j < ng;
            qs_[t] = ok ? qg[j] : 0.f;
            jx[t] = ok ? pg[(size_t)j*3+0] : 0.f;
            jy[t] = ok ? pg[(size_t)j*3+1] : 0.f;
            jz[t] = ok ? pg[(size_t)j*3+2] : 0.f;
        }
        __syncthreads();
        int i = a * 64 + lane;
        float accu = 0.f;
        if (i < ng) {
            float qi = qg[i];
            float xi = pg[(size_t)i*3+0], yi = pg[(size_t)i*3+1], zi = pg[(size_t)i*3+2];
            #pragma unroll 4
            for (int k = 0; k < 16; ++k) {
                int jj = w * 16 + k;                  // wave-uniform -> LDS broadcast
                int j = b * 64 + jj;
                float dx = xi - jx[jj], dy = yi - jy[jj], dz = zi - jz[jj];
                float d2 = dx*dx + dy*dy + dz*dz + 1e-12f;
                float rinv = __frsqrt_rn(d2);
                float r = d2 * rinv;
                float x = 0.5f * r;
                float tt = __frcp_rn(1.f + 0.3275911f * x);
                float poly = ((((1.061405429f*tt - 1.453152027f)*tt + 1.421413741f)*tt
                               - 0.284496736f)*tt + 0.254829592f)*tt;
                float erfv = 1.f - poly * __expf(-x * x);
                float kern = (j == i) ? 0.f : erfv * rinv;
                accu += qi * qs_[jj] * kern;
            }
        }
        accu = wred(accu);
        if (lane == 0) sh[256 + w] = accu;
        __syncthreads();
        if (t == 0) {
            float s = sh[256] + sh[257] + sh[258] + sh[259];
            atomicAdd(&out[g], (a == b) ? 0.5f * s : s);
        }
    } else {
        float se0 = 0.f, sq = 0.f, p0 = 0.f, p1 = 0.f, p2 = 0.f, s0 = 0.f, s1 = 0.f;
        for (int n = g * ng + t; n < (g + 1) * ng; n += 256) {
            int sp = spec[n];
            float fq = fc[sp];
            se0 += ae[sp];
            sq += q[n];
            p0 += fq * pos[(size_t)n*3+0];
            p1 += fq * pos[(size_t)n*3+1];
            p2 += fq * pos[(size_t)n*3+2];
        }
        if (t < 250) {
            int b = g * 250 + t;
            s0 = nEpart[b];
            s1 = nEpart[NUB + b];
        }
        for (int b = t; b < EGB; b += 256) {
            p0 += polpart[b * (GG * 3) + g * 3 + 0];
            p1 += polpart[b * (GG * 3) + g * 3 + 1];
            p2 += polpart[b * (GG * 3) + g * 3 + 2];
        }
        float vals[7] = {se0, s0, s1, sq, p0, p1, p2};
        float* red = sh;
        #pragma unroll
        for (int k = 0; k < 7; ++k) {
            float r = wred(vals[k]);
            if (lane == 0) red[w * 8 + k] = r;
        }
        __syncthreads();
        if (t < 7) sh[64 + t] = red[t] + red[8 + t] + red[16 + t] + red[24 + t];
        __syncthreads();
        if (t == 0) {
            float a0 = sh[64], a1 = sh[65], a2 = sh[66];
            atomicAdd(&out[g], a0 + a1 + a2);
            float* contrib = out + GG + N_;
            contrib[g*3+0] = a0; contrib[g*3+1] = a1; contrib[g*3+2] = a2;
            float* pol = contrib + GG * 3;
            pol[g*3+0] = sh[68]; pol[g*3+1] = sh[69]; pol[g*3+2] = sh[70];
            float* qt = pol + GG * 3;
            qt[g] = sh[67];
        }
    }
}

extern "C" void kernel_launch(void* const* d_in, const int* in_sizes, int n_in,
                              void* d_out, int out_size, void* d_ws, size_t ws_size,
                              hipStream_t stream)
{
    const float* node_attrs      = (const float*)d_in[0];
    const float* positions       = (const float*)d_in[1];
    const int*   edge_index      = (const int*)d_in[2];
    const float* atomic_energies = (const float*)d_in[5];
    const float* embed_w         = (const float*)d_in[6];
    const float* radial_w1       = (const float*)d_in[7];
    const float* radial_b1       = (const float*)d_in[8];
    const float* radial_w2       = (const float*)d_in[9];
    const float* prod_w          = (const float*)d_in[10];
    const float* readout_w       = (const float*)d_in[11];
    const float* ro2_w1          = (const float*)d_in[12];
    const float* ro2_b1          = (const float*)d_in[13];
    const float* ro2_w2          = (const float*)d_in[14];
    const float* charge_w        = (const float*)d_in[15];
    const float* flux_w          = (const float*)d_in[16];
    const float* formal_charges  = (const float*)d_in[17];

    int N = in_sizes[0] / NEL;     // 20000
    int E = in_sizes[2] / 2;       // 320000
    int ng = N / GG;               // 1000

    float* ws      = (float*)d_ws;
    float* scal_a  = ws;                                   // [N,64] layer-0 input
    float* scal_b  = scal_a + (size_t)N * FD;              // [N,64] layer-0 out / layer-1 in
    int*   cnt     = (int*)(scal_b + (size_t)N * FD);      // [N]  (memset)
    int*   cur     = cnt + N;                              // [N]  (scan -> geom-mutated to end offsets)
    uint2* recs    = (uint2*)(cur + N);                    // [E] {snd|rcv<<16, len} sorted
    float* q       = (float*)(recs + E);                   // [N]
    int*   spec    = (int*)(q + N);                        // [N]
    float* nEpart  = (float*)(spec + N);                   // [2*NUB]
    float* polpart = nEpart + 2 * NUB;                     // [EGB*60]
    float* tab     = polpart + EGB * (GG * 3);             // [2][TKNOT][64] float2 paired

    float* out = (float*)d_out;
    float* out_nodeE = out + GG;

    hipMemsetAsync(cnt, 0, (size_t)N * sizeof(int), stream);

    hist_k<<<E / 256, 256, 0, stream>>>(edge_index, cnt, E);
    scan_k<<<1, 1024, 0, stream>>>(cnt, cur, N);
    setup_geom_k<<<EGB + TBBLK + (N * FD) / 256, 256, 0, stream>>>(
        positions, edge_index, flux_w, cur, recs, polpart,
        node_attrs, atomic_energies, formal_charges, embed_w,
        spec, q, out, scal_a, radial_w1, radial_b1, radial_w2, tab, N, E, ng);

    // layer 0: scal_a -> scal_b ; layer 1 (last): reads scal_b, no scal write
    edge_node_k<<<N / 16, 256, 0, stream>>>(
        recs, tab, cur, scal_a, scal_b, spec, prod_w, readout_w,
        ro2_w1, ro2_b1, ro2_w2, charge_w, q, out_nodeE, nEpart, 0, 0, N);
    edge_node_k<<<N / 16, 256, 0, stream>>>(
        recs, tab, cur, scal_b, scal_a, spec, prod_w, readout_w,
        ro2_w1, ro2_b1, ro2_w2, charge_w, q, out_nodeE, nEpart, 1, 1, N);

    coulomb_final_k<<<GG * 137, 256, 0, stream>>>(
        q, positions, spec, atomic_energies, formal_charges,
        nEpart, polpart, out, N, ng);
}